// Round 4
// baseline (313.648 us; speedup 1.0000x reference)
//
#include <hip/hip_runtime.h>
#include <math.h>

// Converse2D (USRNet closed-form prox), s=2, B=4, C=64, H=W=128, K=5.
// Single kernel. Per (b,c): fwd 128x128 FFT in LDS (R2-verified structure,
// ST2=129 odd stride -> 0 bank conflicts), spectrum kept in 32 VGPRs, then two
// {analytic K-mult + inv FFT} passes packing the 4 output polyphases.
// K(q,r) computed per-point in registers: r-dependent factors (P0/P1) hoisted
// per-thread (one column per thread), q wave-uniform.

__device__ __forceinline__ float2 cmulf(float2 a, float2 b){
    return make_float2(a.x*b.x - a.y*b.y, a.x*b.y + a.y*b.x);
}
__device__ __forceinline__ float2 cmulcf(float2 a, float2 b){ // a * conj(b)
    return make_float2(a.x*b.x + a.y*b.y, a.y*b.x - a.x*b.y);
}
__device__ __forceinline__ float2 caddf(float2 a, float2 b){ return make_float2(a.x+b.x, a.y+b.y); }
__device__ __forceinline__ float2 csubf(float2 a, float2 b){ return make_float2(a.x-b.x, a.y-b.y); }
__device__ __forceinline__ float2 cconjf(float2 a){ return make_float2(a.x, -a.y); }

// K value at frequency (q,r) (both already bit-reversed back to natural order).
// P0/P1: per-thread r-contraction of the 5x5 kernel. zq = e^{-2pi i q/256},
// zr = e^{-2pi i r/256}. gscale = 1/(lam*65536). which: 0 = even out rows (kA),
// 1 = odd out rows (kB).
__device__ __forceinline__ float2 kval(const float2* __restrict__ P0,
                                       const float2* __restrict__ P1,
                                       float2 zr, float2 zq, float lam,
                                       float gscale, int which)
{
    float2 zq2 = cmulf(zq, zq);
    float2 F[4]; // [i*2+k]: FB at (q+128i, r+128k)
    #pragma unroll
    for (int k = 0; k < 2; ++k) {
        const float2* P = k ? P1 : P0;
        float2 t0 = cmulcf(P[0], zq2);   // P[a]*zq^{2-a} terms
        float2 t1 = cmulcf(P[1], zq);
        float2 t3 = cmulf(zq,  P[3]);
        float2 t4 = cmulf(zq2, P[4]);
        float2 even = caddf(caddf(t0, t4), P[2]);
        float2 odd  = caddf(t1, t3);
        F[0*2+k] = caddf(even, odd);     // sum_a zq^{a-2} P[a]
        F[1*2+k] = csubf(even, odd);     // alternating (q+128 alias)
    }
    float2 Du0 = make_float2(1.f + zq.x,  zq.y);
    float2 Du1 = make_float2(1.f - zq.x, -zq.y);
    float2 Dv0 = make_float2(1.f + zr.x,  zr.y);
    float2 Dv1 = make_float2(1.f - zr.x, -zr.y);
    float2 DD[4] = { cmulf(Du0,Dv0), cmulf(Du0,Dv1), cmulf(Du1,Dv0), cmulf(Du1,Dv1) };
    float invW = 0.f;
    float2 M = make_float2(0.f, 0.f);
    float2 R[4];
    #pragma unroll
    for (int n = 0; n < 4; ++n) {
        float2 f = F[n];
        R[n] = make_float2(f.x + lam*DD[n].x, -f.y + lam*DD[n].y); // conj(F)+lam*Du*Dv
        invW += f.x*f.x + f.y*f.y;
        M = caddf(M, cmulf(f, R[n]));
    }
    invW *= 0.25f;
    float vs = 1.0f / (invW + lam);
    float2 V = make_float2(M.x*0.25f*vs, M.y*0.25f*vs);
    float2 G[4];
    #pragma unroll
    for (int n = 0; n < 4; ++n) {
        float2 t = cmulf(cconjf(F[n]), V);
        G[n] = make_float2((R[n].x - t.x)*gscale, (R[n].y - t.y)*gscale);
    }
    float2 Sa = caddf(G[0], G[1]), Sb = caddf(G[2], G[3]);
    float2 Da = csubf(G[0], G[1]), Db = csubf(G[2], G[3]);
    float2 h0, h1;
    if (which == 0) {
        h0 = caddf(Sa, Sb);                               // Gh00
        h1 = cmulcf(caddf(Da, Db), zr);                   // Gh01 * phr
    } else {
        h0 = cmulcf(csubf(Sa, Sb), zq);                   // Gh10 * phq
        h1 = cmulcf(cmulcf(csubf(Da, Db), zq), zr);       // Gh11 * phq * phr
    }
    // pack two Hermitian transfers into one complex multiplier: h0 + i*h1
    return make_float2(h0.x - h1.y, h0.y + h1.x);
}

#define ST2 129   // float2 stride: odd -> both row & col passes conflict-free (R2-verified)

template<int AXIS> __device__ __forceinline__ int laddr(int line, int i){
    return AXIS ? (i*ST2 + line) : (line*ST2 + i);
}

// Forward DIF, fused stages (S, S+1). S in {0,2,4}. 4096 quartets, 4/thread.
template<int AXIS, int S>
__device__ __forceinline__ void fwd_pair(float2* Sm, const float2* TW, int tid)
{
    const int h  = 64 >> S;
    const int hh = 32 >> S;
    #pragma unroll
    for (int it = 0; it < 4; ++it) {
        int qid  = it*1024 + tid;
        int line = qid & 127;
        int t    = qid >> 7;
        int blk  = t >> (5 - S);
        int j    = t & (hh - 1);
        int i0   = (blk << (7 - S)) + j;
        int a0 = laddr<AXIS>(line, i0);
        int a1 = laddr<AXIS>(line, i0 + hh);
        int a2 = laddr<AXIS>(line, i0 + h);
        int a3 = laddr<AXIS>(line, i0 + h + hh);
        float2 e0 = Sm[a0], e1 = Sm[a1], e2 = Sm[a2], e3 = Sm[a3];
        float2 w0 = TW[j << S], w1 = TW[(j << S) + 32], w2 = TW[j << (S + 1)];
        float2 u0 = caddf(e0, e2), d0 = cmulf(csubf(e0, e2), w0);
        float2 u1 = caddf(e1, e3), d1 = cmulf(csubf(e1, e3), w1);
        Sm[a0] = caddf(u0, u1);
        Sm[a1] = cmulf(csubf(u0, u1), w2);
        Sm[a2] = caddf(d0, d1);
        Sm[a3] = cmulf(csubf(d0, d1), w2);
    }
}

// Inverse DIT, fused stages (S, S+1). conj twiddles (TW given un-conjugated).
template<int AXIS, int S>
__device__ __forceinline__ void inv_pair(float2* Sm, const float2* TW, int tid)
{
    const int h = 1 << S;
    #pragma unroll
    for (int it = 0; it < 4; ++it) {
        int qid  = it*1024 + tid;
        int line = qid & 127;
        int t    = qid >> 7;
        int blk  = t >> S;
        int j    = t & (h - 1);
        int base = (blk << (S + 2)) + j;
        int a0 = laddr<AXIS>(line, base);
        int a1 = laddr<AXIS>(line, base + h);
        int a2 = laddr<AXIS>(line, base + 2*h);
        int a3 = laddr<AXIS>(line, base + 3*h);
        float2 e0 = Sm[a0], e1 = Sm[a1], e2 = Sm[a2], e3 = Sm[a3];
        float2 cw0 = TW[j << (6 - S)];
        float2 cw1 = TW[j << (5 - S)];
        float2 cw2 = TW[(j << (5 - S)) + 32];
        float2 t1 = cmulcf(e1, cw0);
        float2 A0 = caddf(e0, t1), A1 = csubf(e0, t1);
        float2 t2 = cmulcf(e3, cw0);
        float2 A2 = caddf(e2, t2), A3 = csubf(e2, t2);
        float2 u = cmulcf(A2, cw1);
        Sm[a0] = caddf(A0, u);
        Sm[a2] = csubf(A0, u);
        float2 v = cmulcf(A3, cw2);
        Sm[a1] = caddf(A1, v);
        Sm[a3] = csubf(A1, v);
    }
}

__global__ __launch_bounds__(1024, 4)   // min 4 waves/EU -> 128 VGPR budget, no spills
void converse_main(const float* __restrict__ x, const float* __restrict__ weight,
                   const float* __restrict__ bias, const float* __restrict__ lam_ptr,
                   float* __restrict__ out)
{
    __shared__ float2 S[128 * ST2];
    __shared__ float2 TW[64];

    const int tid = threadIdx.x;
    const int bc  = blockIdx.x;       // [0,256) = b*64 + c
    const int c   = bc & 63;

    if (tid < 64) {
        float s_, c_;
        __sincosf(-6.28318530717958647692f * (float)tid * (1.0f/128.0f), &s_, &c_);
        TW[tid] = make_float2(c_, s_);
    }

    // ---- load x[b,c] as {x, 0} ----
    const float* xp = x + (size_t)bc * 16384;
    #pragma unroll
    for (int it = 0; it < 16; ++it) {
        int n = it * 1024 + tid;
        S[(n >> 7) * ST2 + (n & 127)] = make_float2(xp[n], 0.0f);
    }
    __syncthreads();

    // ---- forward rows (along n): fused (0,1),(2,3),(4,5), single 6 ----
    fwd_pair<0,0>(S, TW, tid); __syncthreads();
    fwd_pair<0,2>(S, TW, tid); __syncthreads();
    fwd_pair<0,4>(S, TW, tid); __syncthreads();
    #pragma unroll
    for (int it = 0; it < 8; ++it) {     // stage 6: pairs (2k,2k+1), twiddle 1
        int g = it*1024 + tid;
        int line = g & 127, k = g >> 7;
        int a = line*ST2 + 2*k;
        float2 u = S[a], v = S[a+1];
        S[a]   = caddf(u, v);
        S[a+1] = csubf(u, v);
    }
    __syncthreads();

    // ---- forward cols (along m): fused (0,1),(2,3),(4,5) ----
    fwd_pair<1,0>(S, TW, tid); __syncthreads();
    fwd_pair<1,2>(S, TW, tid); __syncthreads();
    fwd_pair<1,4>(S, TW, tid); __syncthreads();

    // ---- forward col stage 6 into registers (spectrum kept for both passes) ----
    float2 sA[8], sB[8];
    #pragma unroll
    for (int it = 0; it < 8; ++it) {
        int g = it*1024 + tid;
        int nn = g & 127, j = g >> 7;
        int a = (2*j)*ST2 + nn;
        float2 u = S[a], v = S[a + ST2];
        sA[it] = caddf(u, v);
        sB[it] = csubf(u, v);
    }
    // no barrier needed: each thread re-writes only its own addresses in the mult

    // ---- per-thread K precomputation (r-dependent factors, one column/thread) ----
    const int nn0 = tid & 127;
    const int b0  = tid >> 7;
    const float lam = lam_ptr[0];
    const float gscale = (1.0f / lam) * (1.0f / 65536.0f);  // 1/lam * ifft*polyphase scale
    const float* wc = weight + c * 25;   // block-uniform -> scalar loads

    const int r = (int)(__brev((unsigned)nn0) >> 25);
    float2 zr;
    {
        float s_, c_;
        __sincosf(-6.28318530717958647692f * (float)r * (1.0f/256.0f), &s_, &c_);
        zr = make_float2(c_, s_);
    }
    float2 zr2 = cmulf(zr, zr);
    float2 er0 = cconjf(zr2), er1 = cconjf(zr);
    float2 P0r[5], P1r[5];
    #pragma unroll
    for (int a = 0; a < 5; ++a) {
        float w0 = wc[a*5+0], w1 = wc[a*5+1], w2 = wc[a*5+2], w3 = wc[a*5+3], w4 = wc[a*5+4];
        float2 t0 = make_float2(er0.x*w0, er0.y*w0);
        float2 t1 = make_float2(er1.x*w1, er1.y*w1);
        float2 t3 = make_float2(zr.x*w3,  zr.y*w3);
        float2 t4 = make_float2(zr2.x*w4, zr2.y*w4);
        float2 even = caddf(caddf(t0, t4), make_float2(w2, 0.f));
        float2 odd  = caddf(t1, t3);
        P0r[a] = caddf(even, odd);
        P1r[a] = csubf(even, odd);
    }

    // zq base: q00 = bitrev7(2*b0); per it, q = q00 + bitrev3(it); odd rows +64.
    const int q00 = (int)(__brev((unsigned)(2 * b0)) >> 25);
    float2 zq00;
    {
        float s_, c_;
        __sincosf(-6.28318530717958647692f * (float)q00 * (1.0f/256.0f), &s_, &c_);
        zq00 = make_float2(c_, s_);
    }
    // CK8[k] = e^{-2 pi i k/256}, indexed by bitrev3(it); constants fold under full unroll
    const float2 CK8[8] = {
        make_float2(1.0f, 0.0f),
        make_float2(0.99969881869620425f, -0.02454122852291229f),
        make_float2(0.99879545620517241f, -0.04906767432741801f),
        make_float2(0.99729045667869021f, -0.07356456359966743f),
        make_float2(0.99518472667219693f, -0.09801714032956060f),
        make_float2(0.99247953459870997f, -0.12241067519921620f),
        make_float2(0.98917650996478101f, -0.14673047445536175f),
        make_float2(0.98527764238894122f, -0.17096188876030122f)
    };
    const int BRV3[8] = {0, 4, 2, 6, 1, 5, 3, 7};

    const float bv = bias[c];
    float* op = out + (size_t)bc * 65536;

    #pragma unroll 1
    for (int pass = 0; pass < 2; ++pass) {
        // ---- analytic K-mult (regs) fused with inverse col stage 0 (h=1, w=1) ----
        #pragma unroll
        for (int it = 0; it < 8; ++it) {
            int j = it*8 + b0;                       // LDS rows 2j, 2j+1
            float2 zq_e = cmulf(zq00, CK8[BRV3[it]]);             // e^{-2pi i q/256}
            float2 zq_o = make_float2(zq_e.y, -zq_e.x);           // q+64
            float2 kEv = kval(P0r, P1r, zr, zq_e, lam, gscale, pass);
            float2 kOv = kval(P0r, P1r, zr, zq_o, lam, gscale, pass);
            float2 w0 = cmulf(sA[it], kEv);
            float2 w1 = cmulf(sB[it], kOv);
            int a = (2*j)*ST2 + nn0;
            S[a]       = caddf(w0, w1);
            S[a + ST2] = csubf(w0, w1);
        }
        __syncthreads();

        // ---- inverse cols: fused (1,2),(3,4),(5,6) ----
        inv_pair<1,1>(S, TW, tid); __syncthreads();
        inv_pair<1,3>(S, TW, tid); __syncthreads();
        inv_pair<1,5>(S, TW, tid); __syncthreads();

        // ---- inverse rows: fused (0,1),(2,3),(4,5) ----
        inv_pair<0,0>(S, TW, tid); __syncthreads();
        inv_pair<0,2>(S, TW, tid); __syncthreads();
        inv_pair<0,4>(S, TW, tid); __syncthreads();

        // ---- inverse row stage 6 fused with store (Re->even col, Im->odd col) ----
        #pragma unroll
        for (int it = 0; it < 8; ++it) {
            int g = it*1024 + tid;
            int j = g & 63, m = g >> 6;
            int a = m*ST2 + j;
            float2 u = S[a], v = S[a + 64];
            float2 t = cmulcf(v, TW[j]);
            float2 o0 = caddf(u, t);
            float2 o1 = csubf(u, t);
            size_t ro = (size_t)(2*m + pass) * 256;
            *(float2*)(op + ro + 2*j)       = make_float2(o0.x + bv, o0.y + bv);
            *(float2*)(op + ro + 2*j + 128) = make_float2(o1.x + bv, o1.y + bv);
        }
        __syncthreads();   // protect S from next pass's mult writes
    }
}

extern "C" void kernel_launch(void* const* d_in, const int* in_sizes, int n_in,
                              void* d_out, int out_size, void* d_ws, size_t ws_size,
                              hipStream_t stream)
{
    const float* x      = (const float*)d_in[0];   // [4,64,128,128]
    const float* weight = (const float*)d_in[1];   // [1,64,5,5]
    const float* bias   = (const float*)d_in[2];   // [1,64,1,1]
    const float* lam    = (const float*)d_in[3];   // [1,1,1,1]
    float* out = (float*)d_out;                    // [4,64,256,256]

    hipLaunchKernelGGL(converse_main, dim3(256), dim3(1024), 0, stream,
                       x, weight, bias, lam, out);
}

// Round 5
// 200.854 us; speedup vs baseline: 1.5616x; 1.5616x over previous
//
#include <hip/hip_runtime.h>
#include <math.h>

// Converse2D (USRNet closed-form prox), s=2, B=4, C=64, H=W=128, K=5.
// Single kernel. Per (b,c): fwd 128x128 FFT in LDS (R2-verified structure,
// ST2=129 odd stride -> 0 bank conflicts), spectrum kept in 32 VGPRs, then two
// {analytic K-mult + inv FFT} passes packing the 4 output polyphases.
// K(q,r) computed in registers, BOTH pass multipliers from one shared evaluation.
// amdgpu_waves_per_eu(4,4) forces the 128-VGPR budget (LDS caps us at 1 block/CU
// anyway); R4 showed __launch_bounds__ alone leaves the 64-VGPR default -> spills.

__device__ __forceinline__ float2 cmulf(float2 a, float2 b){
    return make_float2(a.x*b.x - a.y*b.y, a.x*b.y + a.y*b.x);
}
__device__ __forceinline__ float2 cmulcf(float2 a, float2 b){ // a * conj(b)
    return make_float2(a.x*b.x + a.y*b.y, a.y*b.x - a.x*b.y);
}
__device__ __forceinline__ float2 caddf(float2 a, float2 b){ return make_float2(a.x+b.x, a.y+b.y); }
__device__ __forceinline__ float2 csubf(float2 a, float2 b){ return make_float2(a.x-b.x, a.y-b.y); }
__device__ __forceinline__ float2 cconjf(float2 a){ return make_float2(a.x, -a.y); }

// Both packed multipliers at frequency (q,r): kA (even out rows), kB (odd out rows).
// P0/P1: per-thread r-contraction of the 5x5 kernel. zq = e^{-2pi i q/256},
// zr = e^{-2pi i r/256}. gscale = 1/(lam*65536).
__device__ __forceinline__ void kval_pair(const float2* __restrict__ P0,
                                          const float2* __restrict__ P1,
                                          float2 zr, float2 zq, float lam,
                                          float gscale, float2 &kA, float2 &kB)
{
    float2 zq2 = cmulf(zq, zq);
    float2 F[4]; // [i*2+k]: FB at (q+128i, r+128k)
    #pragma unroll
    for (int k = 0; k < 2; ++k) {
        const float2* P = k ? P1 : P0;
        float2 t0 = cmulcf(P[0], zq2);
        float2 t1 = cmulcf(P[1], zq);
        float2 t3 = cmulf(zq,  P[3]);
        float2 t4 = cmulf(zq2, P[4]);
        float2 even = caddf(caddf(t0, t4), P[2]);
        float2 odd  = caddf(t1, t3);
        F[0*2+k] = caddf(even, odd);
        F[1*2+k] = csubf(even, odd);
    }
    float2 Du0 = make_float2(1.f + zq.x,  zq.y);
    float2 Du1 = make_float2(1.f - zq.x, -zq.y);
    float2 Dv0 = make_float2(1.f + zr.x,  zr.y);
    float2 Dv1 = make_float2(1.f - zr.x, -zr.y);
    float2 DD[4] = { cmulf(Du0,Dv0), cmulf(Du0,Dv1), cmulf(Du1,Dv0), cmulf(Du1,Dv1) };
    float invW = 0.f;
    float2 M = make_float2(0.f, 0.f);
    float2 R[4];
    #pragma unroll
    for (int n = 0; n < 4; ++n) {
        float2 f = F[n];
        R[n] = make_float2(f.x + lam*DD[n].x, -f.y + lam*DD[n].y); // conj(F)+lam*Du*Dv
        invW += f.x*f.x + f.y*f.y;
        M = caddf(M, cmulf(f, R[n]));
    }
    invW *= 0.25f;
    float vs = 1.0f / (invW + lam);
    float2 V = make_float2(M.x*0.25f*vs, M.y*0.25f*vs);
    float2 G[4];
    #pragma unroll
    for (int n = 0; n < 4; ++n) {
        float2 t = cmulf(cconjf(F[n]), V);
        G[n] = make_float2((R[n].x - t.x)*gscale, (R[n].y - t.y)*gscale);
    }
    float2 Sa = caddf(G[0], G[1]), Sb = caddf(G[2], G[3]);
    float2 Da = csubf(G[0], G[1]), Db = csubf(G[2], G[3]);
    // even rows: h0 = Gh00, h1 = Gh01*phr; pack h0 + i*h1
    {
        float2 h0 = caddf(Sa, Sb);
        float2 h1 = cmulcf(caddf(Da, Db), zr);
        kA = make_float2(h0.x - h1.y, h0.y + h1.x);
    }
    // odd rows: h0 = Gh10*phq, h1 = Gh11*phq*phr
    {
        float2 h0 = cmulcf(csubf(Sa, Sb), zq);
        float2 h1 = cmulcf(cmulcf(csubf(Da, Db), zq), zr);
        kB = make_float2(h0.x - h1.y, h0.y + h1.x);
    }
}

#define ST2 129   // float2 stride: odd -> both row & col passes conflict-free (R2-verified)

template<int AXIS> __device__ __forceinline__ int laddr(int line, int i){
    return AXIS ? (i*ST2 + line) : (line*ST2 + i);
}

// Forward DIF, fused stages (S, S+1). S in {0,2,4}. 4096 quartets, 4/thread.
template<int AXIS, int S>
__device__ __forceinline__ void fwd_pair(float2* Sm, const float2* TW, int tid)
{
    const int h  = 64 >> S;
    const int hh = 32 >> S;
    #pragma unroll
    for (int it = 0; it < 4; ++it) {
        int qid  = it*1024 + tid;
        int line = qid & 127;
        int t    = qid >> 7;
        int blk  = t >> (5 - S);
        int j    = t & (hh - 1);
        int i0   = (blk << (7 - S)) + j;
        int a0 = laddr<AXIS>(line, i0);
        int a1 = laddr<AXIS>(line, i0 + hh);
        int a2 = laddr<AXIS>(line, i0 + h);
        int a3 = laddr<AXIS>(line, i0 + h + hh);
        float2 e0 = Sm[a0], e1 = Sm[a1], e2 = Sm[a2], e3 = Sm[a3];
        float2 w0 = TW[j << S], w1 = TW[(j << S) + 32], w2 = TW[j << (S + 1)];
        float2 u0 = caddf(e0, e2), d0 = cmulf(csubf(e0, e2), w0);
        float2 u1 = caddf(e1, e3), d1 = cmulf(csubf(e1, e3), w1);
        Sm[a0] = caddf(u0, u1);
        Sm[a1] = cmulf(csubf(u0, u1), w2);
        Sm[a2] = caddf(d0, d1);
        Sm[a3] = cmulf(csubf(d0, d1), w2);
    }
}

// Inverse DIT, fused stages (S, S+1). conj twiddles (TW given un-conjugated).
template<int AXIS, int S>
__device__ __forceinline__ void inv_pair(float2* Sm, const float2* TW, int tid)
{
    const int h = 1 << S;
    #pragma unroll
    for (int it = 0; it < 4; ++it) {
        int qid  = it*1024 + tid;
        int line = qid & 127;
        int t    = qid >> 7;
        int blk  = t >> S;
        int j    = t & (h - 1);
        int base = (blk << (S + 2)) + j;
        int a0 = laddr<AXIS>(line, base);
        int a1 = laddr<AXIS>(line, base + h);
        int a2 = laddr<AXIS>(line, base + 2*h);
        int a3 = laddr<AXIS>(line, base + 3*h);
        float2 e0 = Sm[a0], e1 = Sm[a1], e2 = Sm[a2], e3 = Sm[a3];
        float2 cw0 = TW[j << (6 - S)];
        float2 cw1 = TW[j << (5 - S)];
        float2 cw2 = TW[(j << (5 - S)) + 32];
        float2 t1 = cmulcf(e1, cw0);
        float2 A0 = caddf(e0, t1), A1 = csubf(e0, t1);
        float2 t2 = cmulcf(e3, cw0);
        float2 A2 = caddf(e2, t2), A3 = csubf(e2, t2);
        float2 u = cmulcf(A2, cw1);
        Sm[a0] = caddf(A0, u);
        Sm[a2] = csubf(A0, u);
        float2 v = cmulcf(A3, cw2);
        Sm[a1] = caddf(A1, v);
        Sm[a3] = csubf(A1, v);
    }
}

__global__ __attribute__((amdgpu_flat_work_group_size(1024,1024), amdgpu_waves_per_eu(4,4)))
void converse_main(const float* __restrict__ x, const float* __restrict__ weight,
                   const float* __restrict__ bias, const float* __restrict__ lam_ptr,
                   float* __restrict__ out)
{
    __shared__ float2 S[128 * ST2];
    __shared__ float2 TW[64];

    const int tid = threadIdx.x;
    const int bc  = blockIdx.x;       // [0,256) = b*64 + c
    const int c   = bc & 63;

    if (tid < 64) {
        float s_, c_;
        __sincosf(-6.28318530717958647692f * (float)tid * (1.0f/128.0f), &s_, &c_);
        TW[tid] = make_float2(c_, s_);
    }

    // ---- load x[b,c] as {x, 0} ----
    const float* xp = x + (size_t)bc * 16384;
    #pragma unroll
    for (int it = 0; it < 16; ++it) {
        int n = it * 1024 + tid;
        S[(n >> 7) * ST2 + (n & 127)] = make_float2(xp[n], 0.0f);
    }
    __syncthreads();

    // ---- forward rows (along n): fused (0,1),(2,3),(4,5), single 6 ----
    fwd_pair<0,0>(S, TW, tid); __syncthreads();
    fwd_pair<0,2>(S, TW, tid); __syncthreads();
    fwd_pair<0,4>(S, TW, tid); __syncthreads();
    #pragma unroll
    for (int it = 0; it < 8; ++it) {     // stage 6: pairs (2k,2k+1), twiddle 1
        int g = it*1024 + tid;
        int line = g & 127, k = g >> 7;
        int a = line*ST2 + 2*k;
        float2 u = S[a], v = S[a+1];
        S[a]   = caddf(u, v);
        S[a+1] = csubf(u, v);
    }
    __syncthreads();

    // ---- forward cols (along m): fused (0,1),(2,3),(4,5) ----
    fwd_pair<1,0>(S, TW, tid); __syncthreads();
    fwd_pair<1,2>(S, TW, tid); __syncthreads();
    fwd_pair<1,4>(S, TW, tid); __syncthreads();

    // ---- forward col stage 6 into registers ----
    float2 sA[8], sB[8];
    #pragma unroll
    for (int it = 0; it < 8; ++it) {
        int g = it*1024 + tid;
        int nn = g & 127, j = g >> 7;
        int a = (2*j)*ST2 + nn;
        float2 u = S[a], v = S[a + ST2];
        sA[it] = caddf(u, v);
        sB[it] = csubf(u, v);
    }
    // no barrier needed: each thread re-writes only its own addresses in the mult

    // ---- per-thread K precomputation (r-dependent factors, one column/thread) ----
    const int nn0 = tid & 127;
    const int b0  = tid >> 7;
    const float lam = lam_ptr[0];
    const float gscale = (1.0f / lam) * (1.0f / 65536.0f);
    const float* wc = weight + c * 25;   // block-uniform -> scalar loads

    const int r = (int)(__brev((unsigned)nn0) >> 25);
    float2 zr;
    {
        float s_, c_;
        __sincosf(-6.28318530717958647692f * (float)r * (1.0f/256.0f), &s_, &c_);
        zr = make_float2(c_, s_);
    }
    float2 zr2 = cmulf(zr, zr);
    float2 er0 = cconjf(zr2), er1 = cconjf(zr);
    float2 P0r[5], P1r[5];
    #pragma unroll
    for (int a = 0; a < 5; ++a) {
        float w0 = wc[a*5+0], w1 = wc[a*5+1], w2 = wc[a*5+2], w3 = wc[a*5+3], w4 = wc[a*5+4];
        float2 t0 = make_float2(er0.x*w0, er0.y*w0);
        float2 t1 = make_float2(er1.x*w1, er1.y*w1);
        float2 t3 = make_float2(zr.x*w3,  zr.y*w3);
        float2 t4 = make_float2(zr2.x*w4, zr2.y*w4);
        float2 even = caddf(caddf(t0, t4), make_float2(w2, 0.f));
        float2 odd  = caddf(t1, t3);
        P0r[a] = caddf(even, odd);
        P1r[a] = csubf(even, odd);
    }

    // zq base: q00 = bitrev7(2*b0); per it, q = q00 + bitrev3(it); odd rows +64.
    const int q00 = (int)(__brev((unsigned)(2 * b0)) >> 25);
    float2 zq00;
    {
        float s_, c_;
        __sincosf(-6.28318530717958647692f * (float)q00 * (1.0f/256.0f), &s_, &c_);
        zq00 = make_float2(c_, s_);
    }
    // CK8[k] = e^{-2 pi i k/256}, indexed by bitrev3(it); folds under full unroll
    const float2 CK8[8] = {
        make_float2(1.0f, 0.0f),
        make_float2(0.99969881869620425f, -0.02454122852291229f),
        make_float2(0.99879545620517241f, -0.04906767432741801f),
        make_float2(0.99729045667869021f, -0.07356456359966743f),
        make_float2(0.99518472667219693f, -0.09801714032956060f),
        make_float2(0.99247953459870997f, -0.12241067519921620f),
        make_float2(0.98917650996478101f, -0.14673047445536175f),
        make_float2(0.98527764238894122f, -0.17096188876030122f)
    };
    const int BRV3[8] = {0, 4, 2, 6, 1, 5, 3, 7};

    // ---- one shared K evaluation: pass-0 products -> LDS, pass-1 -> regs ----
    float2 rA[8], rB[8];
    #pragma unroll
    for (int it = 0; it < 8; ++it) {
        int j = it*8 + b0;                       // LDS rows 2j, 2j+1
        float2 zq_e = cmulf(zq00, CK8[BRV3[it]]);         // e^{-2pi i q/256}
        float2 zq_o = make_float2(zq_e.y, -zq_e.x);       // q+64
        float2 kA_e, kB_e, kA_o, kB_o;
        kval_pair(P0r, P1r, zr, zq_e, lam, gscale, kA_e, kB_e);
        kval_pair(P0r, P1r, zr, zq_o, lam, gscale, kA_o, kB_o);
        float2 w0 = cmulf(sA[it], kA_e);
        float2 w1 = cmulf(sB[it], kA_o);
        int a = (2*j)*ST2 + nn0;
        S[a]       = caddf(w0, w1);              // fused inverse col stage 0
        S[a + ST2] = csubf(w0, w1);
        rA[it] = cmulf(sA[it], kB_e);            // pass-1 products replace sA/sB
        rB[it] = cmulf(sB[it], kB_o);
    }

    const float bv = bias[c];
    float* op = out + (size_t)bc * 65536;

    #pragma unroll 1
    for (int pass = 0; pass < 2; ++pass) {
        if (pass == 1) {
            // ---- pass-1 mult results from regs, fused inverse col stage 0 ----
            #pragma unroll
            for (int it = 0; it < 8; ++it) {
                int j = it*8 + b0;
                int a = (2*j)*ST2 + nn0;
                S[a]       = caddf(rA[it], rB[it]);
                S[a + ST2] = csubf(rA[it], rB[it]);
            }
        }
        __syncthreads();

        // ---- inverse cols: fused (1,2),(3,4),(5,6) ----
        inv_pair<1,1>(S, TW, tid); __syncthreads();
        inv_pair<1,3>(S, TW, tid); __syncthreads();
        inv_pair<1,5>(S, TW, tid); __syncthreads();

        // ---- inverse rows: fused (0,1),(2,3),(4,5) ----
        inv_pair<0,0>(S, TW, tid); __syncthreads();
        inv_pair<0,2>(S, TW, tid); __syncthreads();
        inv_pair<0,4>(S, TW, tid); __syncthreads();

        // ---- inverse row stage 6 fused with store (Re->even col, Im->odd col) ----
        #pragma unroll
        for (int it = 0; it < 8; ++it) {
            int g = it*1024 + tid;
            int j = g & 63, m = g >> 6;
            int a = m*ST2 + j;
            float2 u = S[a], v = S[a + 64];
            float2 t = cmulcf(v, TW[j]);
            float2 o0 = caddf(u, t);
            float2 o1 = csubf(u, t);
            size_t ro = (size_t)(2*m + pass) * 256;
            *(float2*)(op + ro + 2*j)       = make_float2(o0.x + bv, o0.y + bv);
            *(float2*)(op + ro + 2*j + 128) = make_float2(o1.x + bv, o1.y + bv);
        }
        __syncthreads();   // stage-6 reads must finish before pass-1 mult writes
    }
}

extern "C" void kernel_launch(void* const* d_in, const int* in_sizes, int n_in,
                              void* d_out, int out_size, void* d_ws, size_t ws_size,
                              hipStream_t stream)
{
    const float* x      = (const float*)d_in[0];   // [4,64,128,128]
    const float* weight = (const float*)d_in[1];   // [1,64,5,5]
    const float* bias   = (const float*)d_in[2];   // [1,64,1,1]
    const float* lam    = (const float*)d_in[3];   // [1,1,1,1]
    float* out = (float*)d_out;                    // [4,64,256,256]

    hipLaunchKernelGGL(converse_main, dim3(256), dim3(1024), 0, stream,
                       x, weight, bias, lam, out);
}